// Round 1
// baseline (4379.851 us; speedup 1.0000x reference)
//
#include <hip/hip_runtime.h>
#include <stdint.h>

typedef unsigned short u16;
typedef __bf16 bf16x8 __attribute__((ext_vector_type(8)));
typedef float f32x4 __attribute__((ext_vector_type(4)));

#define AS1 __attribute__((address_space(1)))
#define AS3 __attribute__((address_space(3)))

__device__ __forceinline__ void ld_lds16(const void* gp, void* lp) {
  __builtin_amdgcn_global_load_lds((AS1 void*)(void*)gp, (AS3 void*)lp, 16, 0, 0);
}

__device__ __forceinline__ u16 f2bf(float f) {
  uint32_t u = __float_as_uint(f);
  u += 0x7FFFu + ((u >> 16) & 1u);
  return (u16)(u >> 16);
}

__device__ __forceinline__ float fsig(float x) { return 1.0f / (1.0f + __expf(-x)); }
__device__ __forceinline__ float ftanhf(float x) {
  float e = __expf(-2.0f * fabsf(x));
  float t = (1.0f - e) / (1.0f + e);
  return copysignf(t, x);
}

#define LSEQ 100
#define EMB 512
#define HID 1024
#define KDIM 1536

// ---------------- LSTM step: z = [x_t; h] @ W' (gates interleaved), fused gate epilogue ----------
__global__ __launch_bounds__(256) void k_step(
    const u16* __restrict__ emb, const u16* __restrict__ W2T,
    const float* __restrict__ b2, const float* __restrict__ p_i,
    const float* __restrict__ p_f, const float* __restrict__ p_o,
    const int* __restrict__ tokQ, const int* __restrict__ tokR,
    const int* __restrict__ lenQ, const int* __restrict__ lenR,
    const u16* __restrict__ h_cur, u16* __restrict__ h_nxt,
    float* __restrict__ c_st, int t)
{
  __shared__ u16 lA[128 * 64];
  __shared__ u16 lB[128 * 64];
  const int tid = threadIdx.x;
  const int lane = tid & 63, wid = tid >> 6;
  const int wm = wid >> 1, wn = wid & 1;
  const int lane_lo = lane & 15, lane_hi = lane >> 4;
  const int bx = blockIdx.x, by = blockIdx.y;

  f32x4 acc[4][4];
  const f32x4 zz = {0.f, 0.f, 0.f, 0.f};
#pragma unroll
  for (int a = 0; a < 4; ++a)
#pragma unroll
    for (int bb = 0; bb < 4; ++bb) acc[a][bb] = zz;

  for (int kt = 0; kt < 24; ++kt) {
    const int kb = kt * 64;
    // stage A (gathered [x_t ; h] rows), swizzled source -> linear LDS dest
#pragma unroll
    for (int j = 0; j < 4; ++j) {
      const int cbase = (j * 4 + wid) * 64;
      const int ch = cbase + lane;
      const int r = ch >> 3;
      const int srcoff = ((((ch & 7) << 4) ^ ((r & 7) << 4)) >> 1);
      const int m = by * 128 + r, e = m >> 9, i = m & 511;
      const u16* src;
      if (kb < 512) {
        const int tok = (e ? tokR : tokQ)[i * LSEQ + t];
        src = emb + (size_t)tok * EMB + kb + srcoff;
      } else {
        src = h_cur + ((size_t)(e * 512 + i)) * HID + (kb - 512) + srcoff;
      }
      ld_lds16(src, &lA[cbase * 8]);
    }
    // stage B (W2T rows = permuted output columns)
#pragma unroll
    for (int j = 0; j < 4; ++j) {
      const int cbase = (j * 4 + wid) * 64;
      const int ch = cbase + lane;
      const int r = ch >> 3;
      const int srcoff = ((((ch & 7) << 4) ^ ((r & 7) << 4)) >> 1);
      const u16* src = W2T + (size_t)(bx * 128 + r) * KDIM + kb + srcoff;
      ld_lds16(src, &lB[cbase * 8]);
    }
    __syncthreads();
#pragma unroll
    for (int kk = 0; kk < 2; ++kk) {
      bf16x8 aF[4], bF[4];
#pragma unroll
      for (int mi = 0; mi < 4; ++mi) {
        const int rr = wm * 64 + mi * 16 + lane_lo;
        const int byo = rr * 128 + ((kk * 64 + lane_hi * 16) ^ ((rr & 7) << 4));
        aF[mi] = *(const bf16x8*)((const char*)lA + byo);
      }
#pragma unroll
      for (int ni = 0; ni < 4; ++ni) {
        const int rr = wn * 64 + ni * 16 + lane_lo;
        const int byo = rr * 128 + ((kk * 64 + lane_hi * 16) ^ ((rr & 7) << 4));
        bF[ni] = *(const bf16x8*)((const char*)lB + byo);
      }
#pragma unroll
      for (int mi = 0; mi < 4; ++mi)
#pragma unroll
        for (int ni = 0; ni < 4; ++ni)
          acc[mi][ni] = __builtin_amdgcn_mfma_f32_16x16x32_bf16(aF[mi], bF[ni], acc[mi][ni], 0, 0, 0);
    }
    __syncthreads();
  }

  // ----- fused gate epilogue: lane owns one h, 16 rows; ni == gate index -----
  const int colbase = bx * 128 + wn * 64;
  const int h = ((colbase >> 6) << 4) + lane_lo;
  float b2v[4];
#pragma unroll
  for (int g = 0; g < 4; ++g) b2v[g] = b2[colbase + g * 16 + lane_lo];
  const float pi = p_i[h], pf = p_f[h], po = p_o[h];

#pragma unroll
  for (int mi = 0; mi < 4; ++mi) {
#pragma unroll
    for (int r = 0; r < 4; ++r) {
      const int m = by * 128 + wm * 64 + mi * 16 + lane_hi * 4 + r;
      const int e = m >> 9, i = m & 511;
      const int len = e ? lenR[i] : lenQ[i];
      const size_t ci = (size_t)(e * 512 + i) * HID + h;
      u16 hv;
      if (t < len) {
        const float c_old = c_st[ci];
        const float zi = acc[mi][0][r] + b2v[0] + pi * c_old;
        const float zj = acc[mi][1][r] + b2v[1];
        const float zf = acc[mi][2][r] + b2v[2] + pf * c_old;  // FORGET_BIAS folded into b2
        const float zo = acc[mi][3][r] + b2v[3];
        const float ig = fsig(zi), fg = fsig(zf);
        const float cn = fg * c_old + ig * ftanhf(zj);
        const float og = fsig(zo + po * cn);
        const float hn = og * ftanhf(cn);
        c_st[ci] = cn;
        hv = f2bf(hn);
      } else {
        hv = h_cur[ci];
      }
      h_nxt[ci] = hv;
    }
  }
}

// ---------------- generic bf16 GEMM: C[m][n] = sum_k A[m][k] * Bn[n][k] ----------------
template <int OUT_BF16>
__global__ __launch_bounds__(256) void k_gemm(
    const u16* __restrict__ A, const u16* __restrict__ Bn,
    void* __restrict__ Cout, int K, int ldc)
{
  __shared__ u16 lA[128 * 64];
  __shared__ u16 lB[128 * 64];
  const int tid = threadIdx.x;
  const int lane = tid & 63, wid = tid >> 6;
  const int wm = wid >> 1, wn = wid & 1;
  const int lane_lo = lane & 15, lane_hi = lane >> 4;
  const int bx = blockIdx.x, by = blockIdx.y;

  f32x4 acc[4][4];
  const f32x4 zz = {0.f, 0.f, 0.f, 0.f};
#pragma unroll
  for (int a = 0; a < 4; ++a)
#pragma unroll
    for (int bb = 0; bb < 4; ++bb) acc[a][bb] = zz;

  const int nkt = K >> 6;
  for (int kt = 0; kt < nkt; ++kt) {
    const int kb = kt * 64;
#pragma unroll
    for (int j = 0; j < 4; ++j) {
      const int cbase = (j * 4 + wid) * 64;
      const int ch = cbase + lane;
      const int r = ch >> 3;
      const int srcoff = ((((ch & 7) << 4) ^ ((r & 7) << 4)) >> 1);
      ld_lds16(A + (size_t)(by * 128 + r) * K + kb + srcoff, &lA[cbase * 8]);
    }
#pragma unroll
    for (int j = 0; j < 4; ++j) {
      const int cbase = (j * 4 + wid) * 64;
      const int ch = cbase + lane;
      const int r = ch >> 3;
      const int srcoff = ((((ch & 7) << 4) ^ ((r & 7) << 4)) >> 1);
      ld_lds16(Bn + (size_t)(bx * 128 + r) * K + kb + srcoff, &lB[cbase * 8]);
    }
    __syncthreads();
#pragma unroll
    for (int kk = 0; kk < 2; ++kk) {
      bf16x8 aF[4], bF[4];
#pragma unroll
      for (int mi = 0; mi < 4; ++mi) {
        const int rr = wm * 64 + mi * 16 + lane_lo;
        const int byo = rr * 128 + ((kk * 64 + lane_hi * 16) ^ ((rr & 7) << 4));
        aF[mi] = *(const bf16x8*)((const char*)lA + byo);
      }
#pragma unroll
      for (int ni = 0; ni < 4; ++ni) {
        const int rr = wn * 64 + ni * 16 + lane_lo;
        const int byo = rr * 128 + ((kk * 64 + lane_hi * 16) ^ ((rr & 7) << 4));
        bF[ni] = *(const bf16x8*)((const char*)lB + byo);
      }
#pragma unroll
      for (int mi = 0; mi < 4; ++mi)
#pragma unroll
        for (int ni = 0; ni < 4; ++ni)
          acc[mi][ni] = __builtin_amdgcn_mfma_f32_16x16x32_bf16(aF[mi], bF[ni], acc[mi][ni], 0, 0, 0);
    }
    __syncthreads();
  }

#pragma unroll
  for (int mi = 0; mi < 4; ++mi)
#pragma unroll
    for (int r = 0; r < 4; ++r) {
      const int m = by * 128 + wm * 64 + mi * 16 + lane_hi * 4 + r;
#pragma unroll
      for (int ni = 0; ni < 4; ++ni) {
        const int col = bx * 128 + wn * 64 + ni * 16 + lane_lo;
        const float v = acc[mi][ni][r];
        if (OUT_BF16) ((u16*)Cout)[(size_t)m * ldc + col] = f2bf(v);
        else ((float*)Cout)[(size_t)m * ldc + col] = v;
      }
    }
}

// ---------------- prep kernels ----------------
// out[n'][k] (bf16) = in[k][n] (f32); perm!=0 applies gate-interleave permutation (N_=4096)
__global__ void k_transpose(const float* __restrict__ in, u16* __restrict__ out,
                            int K_, int N_, int perm)
{
  __shared__ float tile[64][65];
  const int tid = threadIdx.x;
  const int k0 = blockIdx.y * 64, n0 = blockIdx.x * 64;
  const int c = tid & 63, rq = tid >> 6;
  for (int rr = 0; rr < 64; rr += 4)
    tile[rr + rq][c] = in[(size_t)(k0 + rr + rq) * N_ + n0 + c];
  __syncthreads();
  for (int nr0 = 0; nr0 < 64; nr0 += 4) {
    const int nr = nr0 + rq;
    const int n = n0 + nr;
    int np = n;
    if (perm) {
      const int g = n >> 10, hh = n & 1023;
      np = ((hh >> 4) << 6) + (g << 4) + (hh & 15);
    }
    out[(size_t)np * K_ + k0 + c] = f2bf(tile[c][nr]);
  }
}

__global__ void k_bias(const float* __restrict__ b, float* __restrict__ b2) {
  const int n = blockIdx.x * 256 + threadIdx.x;
  if (n < 4096) {
    const int g = n >> 10, hh = n & 1023;
    const int np = ((hh >> 4) << 6) + (g << 4) + (hh & 15);
    b2[np] = b[n] + (g == 2 ? 2.0f : 0.0f);
  }
}

__global__ void k_cvt(const float4* __restrict__ in, u16* __restrict__ out, size_t n4) {
  size_t idx = (size_t)blockIdx.x * blockDim.x + threadIdx.x;
  const size_t stride = (size_t)gridDim.x * blockDim.x;
  for (; idx < n4; idx += stride) {
    const float4 v = in[idx];
    ushort4 o;
    o.x = f2bf(v.x); o.y = f2bf(v.y); o.z = f2bf(v.z); o.w = f2bf(v.w);
    *(ushort4*)(out + idx * 4) = o;
  }
}

__global__ void k_zero(uint4* __restrict__ p, size_t n) {
  size_t idx = (size_t)blockIdx.x * blockDim.x + threadIdx.x;
  const size_t stride = (size_t)gridDim.x * blockDim.x;
  const uint4 z = {0u, 0u, 0u, 0u};
  for (; idx < n; idx += stride) p[idx] = z;
}

// ---------------- loss ----------------
__global__ void k_loss1(const float* __restrict__ D, float* __restrict__ part) {
  __shared__ float sd[256];
  const int tid = threadIdx.x;
  float s = 0.f;
  for (int idx = blockIdx.x * 256 + tid; idx < 512 * 512; idx += 256 * 256) {
    const float x = D[idx];
    float sp;
    if (x > 20.f) sp = x;
    else if (x < -20.f) sp = __expf(x);
    else sp = __logf(1.0f + __expf(x));
    if ((idx >> 9) == (idx & 511)) sp -= x;
    s += sp;
  }
  sd[tid] = s;
  __syncthreads();
  for (int o = 128; o > 0; o >>= 1) { if (tid < o) sd[tid] += sd[tid + o]; __syncthreads(); }
  if (tid == 0) part[blockIdx.x] = sd[0];
}

__global__ void k_loss2(const float* __restrict__ part, float* __restrict__ out) {
  __shared__ float sd[256];
  const int tid = threadIdx.x;
  sd[tid] = part[tid];
  __syncthreads();
  for (int o = 128; o > 0; o >>= 1) { if (tid < o) sd[tid] += sd[tid + o]; __syncthreads(); }
  if (tid == 0) out[0] = sd[0] * (1.0f / (512.0f * 512.0f));
}

// ---------------- launch ----------------
extern "C" void kernel_launch(void* const* d_in, const int* in_sizes, int n_in,
                              void* d_out, int out_size, void* d_ws, size_t ws_size,
                              hipStream_t stream)
{
  const float* embF = (const float*)d_in[0];
  const float* W    = (const float*)d_in[1];
  const float* b    = (const float*)d_in[2];
  const float* p_i  = (const float*)d_in[3];
  const float* p_f  = (const float*)d_in[4];
  const float* p_o  = (const float*)d_in[5];
  const float* Mm   = (const float*)d_in[6];
  const int* tokQ   = (const int*)d_in[7];
  const int* tokR   = (const int*)d_in[8];
  const int* lenQ   = (const int*)d_in[9];
  const int* lenR   = (const int*)d_in[10];
  float* out = (float*)d_out;

  char* ws = (char*)d_ws;
  const size_t OFF_EMB  = 0;                       // 50000*512*2 = 51,200,000
  const size_t OFF_W2T  = 51200000;                // 4096*1536*2 = 12,582,912
  const size_t OFF_MT   = OFF_W2T + 12582912;      // 1024*1024*2 =  2,097,152
  const size_t OFF_B2   = OFF_MT + 2097152;        // 4096*4
  const size_t OFF_H    = OFF_B2 + 16384;          // 2buf*2enc*512*1024*2 = 4,194,304
  const size_t OFF_C    = OFF_H + 4194304;         // 2enc*512*1024*4 = 4,194,304
  const size_t OFF_QT   = OFF_C + 4194304;         // 512*1024*2 = 1,048,576
  const size_t OFF_PART = OFF_QT + 1048576;        // 256*4
  const size_t NEED = OFF_PART + 1024;
  if (ws_size < NEED) return;  // workspace too small: bail (output stays invalid as a signal)

  u16* embB  = (u16*)(ws + OFF_EMB);
  u16* W2T   = (u16*)(ws + OFF_W2T);
  u16* MT    = (u16*)(ws + OFF_MT);
  float* b2  = (float*)(ws + OFF_B2);
  u16* hbuf  = (u16*)(ws + OFF_H);
  float* cst = (float*)(ws + OFF_C);
  u16* qt    = (u16*)(ws + OFF_QT);
  float* part= (float*)(ws + OFF_PART);

  // prep
  k_cvt<<<dim3(2048), dim3(256), 0, stream>>>((const float4*)embF, embB, (size_t)(50000 * 512 / 4));
  k_transpose<<<dim3(64, 24), dim3(256), 0, stream>>>(W, W2T, 1536, 4096, 1);
  k_transpose<<<dim3(16, 16), dim3(256), 0, stream>>>(Mm, MT, 1024, 1024, 0);
  k_bias<<<dim3(16), dim3(256), 0, stream>>>(b, b2);
  k_zero<<<dim3(256), dim3(256), 0, stream>>>((uint4*)hbuf, 131072);   // h buf0 (2 MB)
  k_zero<<<dim3(256), dim3(256), 0, stream>>>((uint4*)cst, 262144);    // c (4 MB)

  // recurrence: h double-buffered; t reads buf (t&1), writes buf ((t+1)&1); final state in buf 0
  const size_t HBUFSTRIDE = (size_t)2 * 512 * 1024;  // u16 elems per buffer
  for (int t = 0; t < 100; ++t) {
    u16* hc = hbuf + (size_t)(t & 1) * HBUFSTRIDE;
    u16* hn = hbuf + (size_t)((t + 1) & 1) * HBUFSTRIDE;
    k_step<<<dim3(32, 8), dim3(256), 0, stream>>>(embB, W2T, b2, p_i, p_f, p_o,
                                                  tokQ, tokR, lenQ, lenR, hc, hn, cst, t);
  }

  // q_t = h_q @ M  (A = enc0 of buf0; B = M^T rows)
  k_gemm<1><<<dim3(8, 4), dim3(256), 0, stream>>>(hbuf, MT, qt, 1024, 1024);
  // distances = q_t @ h_r^T  (B rows = enc1 final h)
  k_gemm<0><<<dim3(4, 4), dim3(256), 0, stream>>>(qt, hbuf + (size_t)512 * 1024, out, 1024, 512);

  k_loss1<<<dim3(256), dim3(256), 0, stream>>>(out, part);
  k_loss2<<<dim3(1), dim3(256), 0, stream>>>(part, out + 262144);
}

// Round 2
// 2662.043 us; speedup vs baseline: 1.6453x; 1.6453x over previous
//
#include <hip/hip_runtime.h>
#include <stdint.h>

typedef unsigned short u16;
typedef __bf16 bf16x8 __attribute__((ext_vector_type(8)));
typedef float f32x4 __attribute__((ext_vector_type(4)));

#define AS1 __attribute__((address_space(1)))
#define AS3 __attribute__((address_space(3)))

__device__ __forceinline__ void ld_lds16(const void* gp, void* lp) {
  __builtin_amdgcn_global_load_lds((AS1 void*)(void*)gp, (AS3 void*)lp, 16, 0, 0);
}

__device__ __forceinline__ u16 f2bf(float f) {
  uint32_t u = __float_as_uint(f);
  u += 0x7FFFu + ((u >> 16) & 1u);
  return (u16)(u >> 16);
}

__device__ __forceinline__ float fsig(float x) { return 1.0f / (1.0f + __expf(-x)); }
__device__ __forceinline__ float ftanhf(float x) {
  float e = __expf(-2.0f * fabsf(x));
  float t = (1.0f - e) / (1.0f + e);
  return copysignf(t, x);
}

#define LSEQ 100
#define EMB 512
#define HID 1024
#define KDIM 1536

// ---------------- LSTM step: z = [x_t; h] @ W' (gates interleaved), fused gate epilogue ----------
// 3-deep LDS pipeline, counted vmcnt (never 0 in loop), raw s_barrier, XCD-swizzled blocks.
__global__ __launch_bounds__(256) void k_step(
    const u16* __restrict__ emb, const u16* __restrict__ W2T,
    const float* __restrict__ b2, const float* __restrict__ p_i,
    const float* __restrict__ p_f, const float* __restrict__ p_o,
    const int* __restrict__ tokQ, const int* __restrict__ tokR,
    const int* __restrict__ lenQ, const int* __restrict__ lenR,
    const u16* __restrict__ h_cur, u16* __restrict__ h_nxt,
    float* __restrict__ c_st, int t)
{
  __shared__ u16 sb[3 * 16384];  // 3 bufs x (lA 8192 + lB 8192) u16 = 96 KB
  const int tid = threadIdx.x;
  const int lane = tid & 63, wid = tid >> 6;
  const int wm = wid >> 1, wn = wid & 1;
  const int lane_lo = lane & 15, lane_hi = lane >> 4;
  // XCD-aware swizzle: 1-D grid of 256; XCD k (= g%8) owns bx in {4k..4k+3}, all by.
  const int g = blockIdx.x;
  const int bx = (g & 7) * 4 + ((g >> 3) & 3);
  const int by = g >> 5;

  f32x4 acc[4][4];
  const f32x4 zz = {0.f, 0.f, 0.f, 0.f};
#pragma unroll
  for (int a = 0; a < 4; ++a)
#pragma unroll
    for (int bb = 0; bb < 4; ++bb) acc[a][bb] = zz;

  // Hoisted per-thread staging pointers (tokens + swizzle folded in; constant over K-loop).
  const u16* pAx[4];
  const u16* pAh[4];
  const u16* pB[4];
  int ldso[4];
#pragma unroll
  for (int j = 0; j < 4; ++j) {
    const int cbase = (j * 4 + wid) * 64;
    const int ch = cbase + lane;
    const int r = ch >> 3;
    const int srcoff = ((((ch & 7) << 4) ^ ((r & 7) << 4)) >> 1);
    const int m = by * 128 + r, e = m >> 9, i = m & 511;
    const int tok = (e ? tokR : tokQ)[i * LSEQ + t];
    pAx[j] = emb + (size_t)tok * EMB + srcoff;
    pAh[j] = h_cur + (size_t)(e * 512 + i) * HID - 512 + srcoff;  // +kb (>=512) stays in-bounds
    pB[j]  = W2T + (size_t)(bx * 128 + r) * KDIM + srcoff;
    ldso[j] = cbase * 8;
  }

  auto stage = [&](int kt, int buf) {
    const int kb = kt * 64;
    u16* lA = sb + buf * 16384;
    u16* lB = lA + 8192;
    const bool isx = kb < EMB;  // uniform per kt
#pragma unroll
    for (int j = 0; j < 4; ++j) {
      ld_lds16((isx ? pAx[j] : pAh[j]) + kb, lA + ldso[j]);
      ld_lds16(pB[j] + kb, lB + ldso[j]);
    }
  };

  auto compute = [&](int buf) {
    const u16* lA = sb + buf * 16384;
    const u16* lB = lA + 8192;
#pragma unroll
    for (int kk = 0; kk < 2; ++kk) {
      bf16x8 aF[4], bF[4];
#pragma unroll
      for (int mi = 0; mi < 4; ++mi) {
        const int rr = wm * 64 + mi * 16 + lane_lo;
        const int byo = rr * 128 + ((kk * 64 + lane_hi * 16) ^ ((rr & 7) << 4));
        aF[mi] = *(const bf16x8*)((const char*)lA + byo);
      }
#pragma unroll
      for (int ni = 0; ni < 4; ++ni) {
        const int rr = wn * 64 + ni * 16 + lane_lo;
        const int byo = rr * 128 + ((kk * 64 + lane_hi * 16) ^ ((rr & 7) << 4));
        bF[ni] = *(const bf16x8*)((const char*)lB + byo);
      }
#pragma unroll
      for (int mi = 0; mi < 4; ++mi)
#pragma unroll
        for (int ni = 0; ni < 4; ++ni)
          acc[mi][ni] = __builtin_amdgcn_mfma_f32_16x16x32_bf16(aF[mi], bF[ni], acc[mi][ni], 0, 0, 0);
    }
  };

  // Pipeline: prologue stages tiles 0,1; per iter: wait oldest tile, barrier, stage kt+2, compute kt.
  stage(0, 0);
  stage(1, 1);
  for (int kt = 0; kt < 24; ++kt) {
    if (kt < 23) asm volatile("s_waitcnt vmcnt(8)" ::: "memory");  // tile kt landed; kt+1 in flight
    else         asm volatile("s_waitcnt vmcnt(0)" ::: "memory");
    __builtin_amdgcn_s_barrier();
    __builtin_amdgcn_sched_barrier(0);
    if (kt < 22) stage(kt + 2, (kt + 2) % 3);
    __builtin_amdgcn_s_setprio(1);
    compute(kt % 3);
    __builtin_amdgcn_s_setprio(0);
  }

  // ----- fused gate epilogue: lane owns one h, 16 rows; ni == gate index -----
  const int colbase = bx * 128 + wn * 64;
  const int h = ((colbase >> 6) << 4) + lane_lo;
  float b2v[4];
#pragma unroll
  for (int gg = 0; gg < 4; ++gg) b2v[gg] = b2[colbase + gg * 16 + lane_lo];
  const float pi = p_i[h], pf = p_f[h], po = p_o[h];

#pragma unroll
  for (int mi = 0; mi < 4; ++mi) {
#pragma unroll
    for (int r = 0; r < 4; ++r) {
      const int m = by * 128 + wm * 64 + mi * 16 + lane_hi * 4 + r;
      const int e = m >> 9, i = m & 511;
      const int len = e ? lenR[i] : lenQ[i];
      const size_t ci = (size_t)(e * 512 + i) * HID + h;
      u16 hv;
      if (t < len) {
        const float c_old = c_st[ci];
        const float zi = acc[mi][0][r] + b2v[0] + pi * c_old;
        const float zj = acc[mi][1][r] + b2v[1];
        const float zf = acc[mi][2][r] + b2v[2] + pf * c_old;  // FORGET_BIAS folded into b2
        const float zo = acc[mi][3][r] + b2v[3];
        const float ig = fsig(zi), fg = fsig(zf);
        const float cn = fg * c_old + ig * ftanhf(zj);
        const float og = fsig(zo + po * cn);
        const float hn = og * ftanhf(cn);
        c_st[ci] = cn;
        hv = f2bf(hn);
      } else {
        hv = h_cur[ci];
      }
      h_nxt[ci] = hv;
    }
  }
}

// ---------------- generic bf16 GEMM: C[m][n] = sum_k A[m][k] * Bn[n][k] ----------------
template <int OUT_BF16>
__global__ __launch_bounds__(256) void k_gemm(
    const u16* __restrict__ A, const u16* __restrict__ Bn,
    void* __restrict__ Cout, int K, int ldc)
{
  __shared__ u16 lA[128 * 64];
  __shared__ u16 lB[128 * 64];
  const int tid = threadIdx.x;
  const int lane = tid & 63, wid = tid >> 6;
  const int wm = wid >> 1, wn = wid & 1;
  const int lane_lo = lane & 15, lane_hi = lane >> 4;
  const int bx = blockIdx.x, by = blockIdx.y;

  f32x4 acc[4][4];
  const f32x4 zz = {0.f, 0.f, 0.f, 0.f};
#pragma unroll
  for (int a = 0; a < 4; ++a)
#pragma unroll
    for (int bb = 0; bb < 4; ++bb) acc[a][bb] = zz;

  const int nkt = K >> 6;
  for (int kt = 0; kt < nkt; ++kt) {
    const int kb = kt * 64;
#pragma unroll
    for (int j = 0; j < 4; ++j) {
      const int cbase = (j * 4 + wid) * 64;
      const int ch = cbase + lane;
      const int r = ch >> 3;
      const int srcoff = ((((ch & 7) << 4) ^ ((r & 7) << 4)) >> 1);
      ld_lds16(A + (size_t)(by * 128 + r) * K + kb + srcoff, &lA[cbase * 8]);
    }
#pragma unroll
    for (int j = 0; j < 4; ++j) {
      const int cbase = (j * 4 + wid) * 64;
      const int ch = cbase + lane;
      const int r = ch >> 3;
      const int srcoff = ((((ch & 7) << 4) ^ ((r & 7) << 4)) >> 1);
      ld_lds16(Bn + (size_t)(bx * 128 + r) * K + kb + srcoff, &lB[cbase * 8]);
    }
    __syncthreads();
#pragma unroll
    for (int kk = 0; kk < 2; ++kk) {
      bf16x8 aF[4], bF[4];
#pragma unroll
      for (int mi = 0; mi < 4; ++mi) {
        const int rr = wm * 64 + mi * 16 + lane_lo;
        const int byo = rr * 128 + ((kk * 64 + lane_hi * 16) ^ ((rr & 7) << 4));
        aF[mi] = *(const bf16x8*)((const char*)lA + byo);
      }
#pragma unroll
      for (int ni = 0; ni < 4; ++ni) {
        const int rr = wn * 64 + ni * 16 + lane_lo;
        const int byo = rr * 128 + ((kk * 64 + lane_hi * 16) ^ ((rr & 7) << 4));
        bF[ni] = *(const bf16x8*)((const char*)lB + byo);
      }
#pragma unroll
      for (int mi = 0; mi < 4; ++mi)
#pragma unroll
        for (int ni = 0; ni < 4; ++ni)
          acc[mi][ni] = __builtin_amdgcn_mfma_f32_16x16x32_bf16(aF[mi], bF[ni], acc[mi][ni], 0, 0, 0);
    }
    __syncthreads();
  }

#pragma unroll
  for (int mi = 0; mi < 4; ++mi)
#pragma unroll
    for (int r = 0; r < 4; ++r) {
      const int m = by * 128 + wm * 64 + mi * 16 + lane_hi * 4 + r;
#pragma unroll
      for (int ni = 0; ni < 4; ++ni) {
        const int col = bx * 128 + wn * 64 + ni * 16 + lane_lo;
        const float v = acc[mi][ni][r];
        if (OUT_BF16) ((u16*)Cout)[(size_t)m * ldc + col] = f2bf(v);
        else ((float*)Cout)[(size_t)m * ldc + col] = v;
      }
    }
}

// ---------------- prep kernels ----------------
// out[n'][k] (bf16) = in[k][n] (f32); perm!=0 applies gate-interleave permutation (N_=4096)
__global__ void k_transpose(const float* __restrict__ in, u16* __restrict__ out,
                            int K_, int N_, int perm)
{
  __shared__ float tile[64][65];
  const int tid = threadIdx.x;
  const int k0 = blockIdx.y * 64, n0 = blockIdx.x * 64;
  const int c = tid & 63, rq = tid >> 6;
  for (int rr = 0; rr < 64; rr += 4)
    tile[rr + rq][c] = in[(size_t)(k0 + rr + rq) * N_ + n0 + c];
  __syncthreads();
  for (int nr0 = 0; nr0 < 64; nr0 += 4) {
    const int nr = nr0 + rq;
    const int n = n0 + nr;
    int np = n;
    if (perm) {
      const int g = n >> 10, hh = n & 1023;
      np = ((hh >> 4) << 6) + (g << 4) + (hh & 15);
    }
    out[(size_t)np * K_ + k0 + c] = f2bf(tile[c][nr]);
  }
}

__global__ void k_bias(const float* __restrict__ b, float* __restrict__ b2) {
  const int n = blockIdx.x * 256 + threadIdx.x;
  if (n < 4096) {
    const int g = n >> 10, hh = n & 1023;
    const int np = ((hh >> 4) << 6) + (g << 4) + (hh & 15);
    b2[np] = b[n] + (g == 2 ? 2.0f : 0.0f);
  }
}

__global__ void k_cvt(const float4* __restrict__ in, u16* __restrict__ out, size_t n4) {
  size_t idx = (size_t)blockIdx.x * blockDim.x + threadIdx.x;
  const size_t stride = (size_t)gridDim.x * blockDim.x;
  for (; idx < n4; idx += stride) {
    const float4 v = in[idx];
    ushort4 o;
    o.x = f2bf(v.x); o.y = f2bf(v.y); o.z = f2bf(v.z); o.w = f2bf(v.w);
    *(ushort4*)(out + idx * 4) = o;
  }
}

__global__ void k_zero(uint4* __restrict__ p, size_t n) {
  size_t idx = (size_t)blockIdx.x * blockDim.x + threadIdx.x;
  const size_t stride = (size_t)gridDim.x * blockDim.x;
  const uint4 z = {0u, 0u, 0u, 0u};
  for (; idx < n; idx += stride) p[idx] = z;
}

// ---------------- loss ----------------
__global__ void k_loss1(const float* __restrict__ D, float* __restrict__ part) {
  __shared__ float sd[256];
  const int tid = threadIdx.x;
  float s = 0.f;
  for (int idx = blockIdx.x * 256 + tid; idx < 512 * 512; idx += 256 * 256) {
    const float x = D[idx];
    float sp;
    if (x > 20.f) sp = x;
    else if (x < -20.f) sp = __expf(x);
    else sp = __logf(1.0f + __expf(x));
    if ((idx >> 9) == (idx & 511)) sp -= x;
    s += sp;
  }
  sd[tid] = s;
  __syncthreads();
  for (int o = 128; o > 0; o >>= 1) { if (tid < o) sd[tid] += sd[tid + o]; __syncthreads(); }
  if (tid == 0) part[blockIdx.x] = sd[0];
}

__global__ void k_loss2(const float* __restrict__ part, float* __restrict__ out) {
  __shared__ float sd[256];
  const int tid = threadIdx.x;
  sd[tid] = part[tid];
  __syncthreads();
  for (int o = 128; o > 0; o >>= 1) { if (tid < o) sd[tid] += sd[tid + o]; __syncthreads(); }
  if (tid == 0) out[0] = sd[0] * (1.0f / (512.0f * 512.0f));
}

// ---------------- launch ----------------
extern "C" void kernel_launch(void* const* d_in, const int* in_sizes, int n_in,
                              void* d_out, int out_size, void* d_ws, size_t ws_size,
                              hipStream_t stream)
{
  const float* embF = (const float*)d_in[0];
  const float* W    = (const float*)d_in[1];
  const float* b    = (const float*)d_in[2];
  const float* p_i  = (const float*)d_in[3];
  const float* p_f  = (const float*)d_in[4];
  const float* p_o  = (const float*)d_in[5];
  const float* Mm   = (const float*)d_in[6];
  const int* tokQ   = (const int*)d_in[7];
  const int* tokR   = (const int*)d_in[8];
  const int* lenQ   = (const int*)d_in[9];
  const int* lenR   = (const int*)d_in[10];
  float* out = (float*)d_out;

  char* ws = (char*)d_ws;
  const size_t OFF_EMB  = 0;                       // 50000*512*2 = 51,200,000
  const size_t OFF_W2T  = 51200000;                // 4096*1536*2 = 12,582,912
  const size_t OFF_MT   = OFF_W2T + 12582912;      // 1024*1024*2 =  2,097,152
  const size_t OFF_B2   = OFF_MT + 2097152;        // 4096*4
  const size_t OFF_H    = OFF_B2 + 16384;          // 2buf*2enc*512*1024*2 = 4,194,304
  const size_t OFF_C    = OFF_H + 4194304;         // 2enc*512*1024*4 = 4,194,304
  const size_t OFF_QT   = OFF_C + 4194304;         // 512*1024*2 = 1,048,576
  const size_t OFF_PART = OFF_QT + 1048576;        // 256*4
  const size_t NEED = OFF_PART + 1024;
  if (ws_size < NEED) return;  // workspace too small: bail (output stays invalid as a signal)

  u16* embB  = (u16*)(ws + OFF_EMB);
  u16* W2T   = (u16*)(ws + OFF_W2T);
  u16* MT    = (u16*)(ws + OFF_MT);
  float* b2  = (float*)(ws + OFF_B2);
  u16* hbuf  = (u16*)(ws + OFF_H);
  float* cst = (float*)(ws + OFF_C);
  u16* qt    = (u16*)(ws + OFF_QT);
  float* part= (float*)(ws + OFF_PART);

  // prep
  k_cvt<<<dim3(2048), dim3(256), 0, stream>>>((const float4*)embF, embB, (size_t)(50000 * 512 / 4));
  k_transpose<<<dim3(64, 24), dim3(256), 0, stream>>>(W, W2T, 1536, 4096, 1);
  k_transpose<<<dim3(16, 16), dim3(256), 0, stream>>>(Mm, MT, 1024, 1024, 0);
  k_bias<<<dim3(16), dim3(256), 0, stream>>>(b, b2);
  k_zero<<<dim3(256), dim3(256), 0, stream>>>((uint4*)hbuf, 131072);   // h buf0 (2 MB)
  k_zero<<<dim3(256), dim3(256), 0, stream>>>((uint4*)cst, 262144);    // c (4 MB)

  // recurrence: h double-buffered; t reads buf (t&1), writes buf ((t+1)&1); final state in buf 0
  const size_t HBUFSTRIDE = (size_t)2 * 512 * 1024;  // u16 elems per buffer
  for (int t = 0; t < 100; ++t) {
    u16* hc = hbuf + (size_t)(t & 1) * HBUFSTRIDE;
    u16* hn = hbuf + (size_t)((t + 1) & 1) * HBUFSTRIDE;
    k_step<<<dim3(256), dim3(256), 0, stream>>>(embB, W2T, b2, p_i, p_f, p_o,
                                                tokQ, tokR, lenQ, lenR, hc, hn, cst, t);
  }

  // q_t = h_q @ M  (A = enc0 of buf0; B = M^T rows)
  k_gemm<1><<<dim3(8, 4), dim3(256), 0, stream>>>(hbuf, MT, qt, 1024, 1024);
  // distances = q_t @ h_r^T  (B rows = enc1 final h)
  k_gemm<0><<<dim3(4, 4), dim3(256), 0, stream>>>(qt, hbuf + (size_t)512 * 1024, out, 1024, 512);

  k_loss1<<<dim3(256), dim3(256), 0, stream>>>(out, part);
  k_loss2<<<dim3(1), dim3(256), 0, stream>>>(part, out + 262144);
}

// Round 3
// 2300.577 us; speedup vs baseline: 1.9038x; 1.1571x over previous
//
#include <hip/hip_runtime.h>
#include <stdint.h>

typedef unsigned short u16;
typedef __bf16 bf16x8 __attribute__((ext_vector_type(8)));
typedef float f32x4 __attribute__((ext_vector_type(4)));

#define AS1 __attribute__((address_space(1)))
#define AS3 __attribute__((address_space(3)))

__device__ __forceinline__ void ld_lds16(const void* gp, void* lp) {
  __builtin_amdgcn_global_load_lds((AS1 void*)(void*)gp, (AS3 void*)lp, 16, 0, 0);
}

__device__ __forceinline__ u16 f2bf(float f) {
  uint32_t u = __float_as_uint(f);
  u += 0x7FFFu + ((u >> 16) & 1u);
  return (u16)(u >> 16);
}

__device__ __forceinline__ float fsig(float x) { return 1.0f / (1.0f + __expf(-x)); }
__device__ __forceinline__ float ftanhf(float x) {
  float e = __expf(-2.0f * fabsf(x));
  float t = (1.0f - e) / (1.0f + e);
  return copysignf(t, x);
}

#define LSEQ 100
#define EMB 512
#define HID 1024
#define KDIM 1536

// ---------------- LSTM step: z = [x_t; h] @ W' (gates interleaved), fused gate epilogue ----------
// BK=128, 2-deep LDS double-buffer (128 KB), 1 barrier + 1 vmcnt wait per K-iter (12 iters),
// epilogue operands prefetched before the K-loop, XCD-swizzled blocks.
__global__ __launch_bounds__(256) void k_step(
    const u16* __restrict__ emb, const u16* __restrict__ W2T,
    const float* __restrict__ b2, const float* __restrict__ p_i,
    const float* __restrict__ p_f, const float* __restrict__ p_o,
    const int* __restrict__ tokQ, const int* __restrict__ tokR,
    const int* __restrict__ lenQ, const int* __restrict__ lenR,
    const u16* __restrict__ h_cur, u16* __restrict__ h_nxt,
    float* __restrict__ c_st, int t)
{
  __shared__ u16 sb[2 * 32768];  // 2 bufs x (lA 16384 u16 + lB 16384 u16) = 128 KB
  const int tid = threadIdx.x;
  const int lane = tid & 63, wid = tid >> 6;
  const int wm = wid >> 1, wn = wid & 1;
  const int lane_lo = lane & 15, lane_hi = lane >> 4;
  // XCD-aware swizzle: XCD k (= g%8) owns bx in {4k..4k+3}, all by.
  const int g = blockIdx.x;
  const int bx = (g & 7) * 4 + ((g >> 3) & 3);
  const int by = g >> 5;

  f32x4 acc[4][4];
  const f32x4 zz = {0.f, 0.f, 0.f, 0.f};
#pragma unroll
  for (int a = 0; a < 4; ++a)
#pragma unroll
    for (int bb = 0; bb < 4; ++bb) acc[a][bb] = zz;

  // ---- token loads first (longest dependency chain) ----
  int tokv[8], rowe[8], rowi[8];
  int ldso[8], srco[8];
#pragma unroll
  for (int j = 0; j < 8; ++j) {
    const int cbase = (j * 4 + wid) * 64;   // chunk base; 16 chunks (256 B) per row
    const int ch = cbase + lane;
    const int r = ch >> 4;
    const int srcoff = (((ch & 15) ^ (r & 7)) << 3);  // XOR-swizzle, elems
    const int m = by * 128 + r, e = m >> 9, i = m & 511;
    tokv[j] = (e ? tokR : tokQ)[i * LSEQ + t];
    rowe[j] = e; rowi[j] = i;
    srco[j] = srcoff;
    ldso[j] = cbase * 8;  // u16 elems (8 per 16 B chunk)
  }

  // ---- B staging pointers + issue tile 0 B ----
  const u16* pB[8];
#pragma unroll
  for (int j = 0; j < 8; ++j) {
    const int cbase = (j * 4 + wid) * 64;
    const int r = (cbase + lane) >> 4;
    pB[j] = W2T + (size_t)(bx * 128 + r) * KDIM + srco[j];
  }

  auto stageB = [&](int kt, int buf) {
    const int kb = kt * 128;
    u16* lB = sb + buf * 32768 + 16384;
#pragma unroll
    for (int j = 0; j < 8; ++j) ld_lds16(pB[j] + kb, lB + ldso[j]);
  };
  stageB(0, 0);

  // ---- A staging pointers (gathered [x_t ; h] rows) + issue tile 0 A ----
  const u16* pAx[8];
  const u16* pAh[8];
#pragma unroll
  for (int j = 0; j < 8; ++j) {
    pAx[j] = emb + (size_t)tokv[j] * EMB + srco[j];
    pAh[j] = h_cur + (size_t)(rowe[j] * 512 + rowi[j]) * HID - 512 + srco[j];  // kb>=512 when used
  }

  auto stageA = [&](int kt, int buf) {
    const int kb = kt * 128;
    u16* lA = sb + buf * 32768;
    const bool isx = kb < EMB;  // uniform per kt
#pragma unroll
    for (int j = 0; j < 8; ++j) ld_lds16((isx ? pAx[j] : pAh[j]) + kb, lA + ldso[j]);
  };
  stageA(0, 0);

  // ---- epilogue operand prefetch (hidden under the K-loop) ----
  const int colbase = bx * 128 + wn * 64;
  const int h = ((colbase >> 6) << 4) + lane_lo;
  float b2v[4];
#pragma unroll
  for (int gg = 0; gg < 4; ++gg) b2v[gg] = b2[colbase + gg * 16 + lane_lo];
  const float pi = p_i[h], pf = p_f[h], po = p_o[h];
  int lenv[4][4];
  float cold[4][4];
  u16 hprev[4][4];
#pragma unroll
  for (int mi = 0; mi < 4; ++mi)
#pragma unroll
    for (int r = 0; r < 4; ++r) {
      const int m = by * 128 + wm * 64 + mi * 16 + lane_hi * 4 + r;
      const int e = m >> 9, i = m & 511;
      lenv[mi][r] = e ? lenR[i] : lenQ[i];
      const size_t ci = (size_t)(e * 512 + i) * HID + h;
      cold[mi][r] = c_st[ci];
      hprev[mi][r] = h_cur[ci];
    }

  auto compute = [&](int buf) {
    const u16* lA = sb + buf * 32768;
    const u16* lB = lA + 16384;
#pragma unroll
    for (int kk = 0; kk < 4; ++kk) {
      bf16x8 aF[4], bF[4];
#pragma unroll
      for (int mi = 0; mi < 4; ++mi) {
        const int rr = wm * 64 + mi * 16 + lane_lo;
        const int byo = rr * 256 + ((kk * 64 + lane_hi * 16) ^ ((rr & 7) << 4));
        aF[mi] = *(const bf16x8*)((const char*)lA + byo);
      }
#pragma unroll
      for (int ni = 0; ni < 4; ++ni) {
        const int rr = wn * 64 + ni * 16 + lane_lo;
        const int byo = rr * 256 + ((kk * 64 + lane_hi * 16) ^ ((rr & 7) << 4));
        bF[ni] = *(const bf16x8*)((const char*)lB + byo);
      }
#pragma unroll
      for (int mi = 0; mi < 4; ++mi)
#pragma unroll
        for (int ni = 0; ni < 4; ++ni)
          acc[mi][ni] = __builtin_amdgcn_mfma_f32_16x16x32_bf16(aF[mi], bF[ni], acc[mi][ni], 0, 0, 0);
    }
  };

  // ---- K loop: 12 iters; per iter: wait tile kt, barrier, stage kt+1, compute kt ----
  for (int kt = 0; kt < 12; ++kt) {
    asm volatile("s_waitcnt vmcnt(0)" ::: "memory");  // only tile kt outstanding in steady state
    __builtin_amdgcn_s_barrier();
    __builtin_amdgcn_sched_barrier(0);
    if (kt < 11) {
      stageB(kt + 1, (kt + 1) & 1);
      stageA(kt + 1, (kt + 1) & 1);
    }
    __builtin_amdgcn_s_setprio(1);
    compute(kt & 1);
    __builtin_amdgcn_s_setprio(0);
  }

  // ----- fused gate epilogue: lane owns one h, 16 rows; ni == gate index -----
#pragma unroll
  for (int mi = 0; mi < 4; ++mi) {
#pragma unroll
    for (int r = 0; r < 4; ++r) {
      const int m = by * 128 + wm * 64 + mi * 16 + lane_hi * 4 + r;
      const int e = m >> 9, i = m & 511;
      const size_t ci = (size_t)(e * 512 + i) * HID + h;
      u16 hv;
      if (t < lenv[mi][r]) {
        const float c_old = cold[mi][r];
        const float zi = acc[mi][0][r] + b2v[0] + pi * c_old;
        const float zj = acc[mi][1][r] + b2v[1];
        const float zf = acc[mi][2][r] + b2v[2] + pf * c_old;  // FORGET_BIAS folded into b2
        const float zo = acc[mi][3][r] + b2v[3];
        const float ig = fsig(zi), fg = fsig(zf);
        const float cn = fg * c_old + ig * ftanhf(zj);
        const float og = fsig(zo + po * cn);
        const float hn = og * ftanhf(cn);
        c_st[ci] = cn;
        hv = f2bf(hn);
      } else {
        hv = hprev[mi][r];
      }
      h_nxt[ci] = hv;
    }
  }
}

// ---------------- generic bf16 GEMM: C[m][n] = sum_k A[m][k] * Bn[n][k] ----------------
template <int OUT_BF16>
__global__ __launch_bounds__(256) void k_gemm(
    const u16* __restrict__ A, const u16* __restrict__ Bn,
    void* __restrict__ Cout, int K, int ldc)
{
  __shared__ u16 lA[128 * 64];
  __shared__ u16 lB[128 * 64];
  const int tid = threadIdx.x;
  const int lane = tid & 63, wid = tid >> 6;
  const int wm = wid >> 1, wn = wid & 1;
  const int lane_lo = lane & 15, lane_hi = lane >> 4;
  const int bx = blockIdx.x, by = blockIdx.y;

  f32x4 acc[4][4];
  const f32x4 zz = {0.f, 0.f, 0.f, 0.f};
#pragma unroll
  for (int a = 0; a < 4; ++a)
#pragma unroll
    for (int bb = 0; bb < 4; ++bb) acc[a][bb] = zz;

  const int nkt = K >> 6;
  for (int kt = 0; kt < nkt; ++kt) {
    const int kb = kt * 64;
#pragma unroll
    for (int j = 0; j < 4; ++j) {
      const int cbase = (j * 4 + wid) * 64;
      const int ch = cbase + lane;
      const int r = ch >> 3;
      const int srcoff = ((((ch & 7) << 4) ^ ((r & 7) << 4)) >> 1);
      ld_lds16(A + (size_t)(by * 128 + r) * K + kb + srcoff, &lA[cbase * 8]);
    }
#pragma unroll
    for (int j = 0; j < 4; ++j) {
      const int cbase = (j * 4 + wid) * 64;
      const int ch = cbase + lane;
      const int r = ch >> 3;
      const int srcoff = ((((ch & 7) << 4) ^ ((r & 7) << 4)) >> 1);
      ld_lds16(Bn + (size_t)(bx * 128 + r) * K + kb + srcoff, &lB[cbase * 8]);
    }
    __syncthreads();
#pragma unroll
    for (int kk = 0; kk < 2; ++kk) {
      bf16x8 aF[4], bF[4];
#pragma unroll
      for (int mi = 0; mi < 4; ++mi) {
        const int rr = wm * 64 + mi * 16 + lane_lo;
        const int byo = rr * 128 + ((kk * 64 + lane_hi * 16) ^ ((rr & 7) << 4));
        aF[mi] = *(const bf16x8*)((const char*)lA + byo);
      }
#pragma unroll
      for (int ni = 0; ni < 4; ++ni) {
        const int rr = wn * 64 + ni * 16 + lane_lo;
        const int byo = rr * 128 + ((kk * 64 + lane_hi * 16) ^ ((rr & 7) << 4));
        bF[ni] = *(const bf16x8*)((const char*)lB + byo);
      }
#pragma unroll
      for (int mi = 0; mi < 4; ++mi)
#pragma unroll
        for (int ni = 0; ni < 4; ++ni)
          acc[mi][ni] = __builtin_amdgcn_mfma_f32_16x16x32_bf16(aF[mi], bF[ni], acc[mi][ni], 0, 0, 0);
    }
    __syncthreads();
  }

#pragma unroll
  for (int mi = 0; mi < 4; ++mi)
#pragma unroll
    for (int r = 0; r < 4; ++r) {
      const int m = by * 128 + wm * 64 + mi * 16 + lane_hi * 4 + r;
#pragma unroll
      for (int ni = 0; ni < 4; ++ni) {
        const int col = bx * 128 + wn * 64 + ni * 16 + lane_lo;
        const float v = acc[mi][ni][r];
        if (OUT_BF16) ((u16*)Cout)[(size_t)m * ldc + col] = f2bf(v);
        else ((float*)Cout)[(size_t)m * ldc + col] = v;
      }
    }
}

// ---------------- prep kernels ----------------
// out[n'][k] (bf16) = in[k][n] (f32); perm!=0 applies gate-interleave permutation (N_=4096)
__global__ void k_transpose(const float* __restrict__ in, u16* __restrict__ out,
                            int K_, int N_, int perm)
{
  __shared__ float tile[64][65];
  const int tid = threadIdx.x;
  const int k0 = blockIdx.y * 64, n0 = blockIdx.x * 64;
  const int c = tid & 63, rq = tid >> 6;
  for (int rr = 0; rr < 64; rr += 4)
    tile[rr + rq][c] = in[(size_t)(k0 + rr + rq) * N_ + n0 + c];
  __syncthreads();
  for (int nr0 = 0; nr0 < 64; nr0 += 4) {
    const int nr = nr0 + rq;
    const int n = n0 + nr;
    int np = n;
    if (perm) {
      const int g = n >> 10, hh = n & 1023;
      np = ((hh >> 4) << 6) + (g << 4) + (hh & 15);
    }
    out[(size_t)np * K_ + k0 + c] = f2bf(tile[c][nr]);
  }
}

__global__ void k_bias(const float* __restrict__ b, float* __restrict__ b2) {
  const int n = blockIdx.x * 256 + threadIdx.x;
  if (n < 4096) {
    const int g = n >> 10, hh = n & 1023;
    const int np = ((hh >> 4) << 6) + (g << 4) + (hh & 15);
    b2[np] = b[n] + (g == 2 ? 2.0f : 0.0f);
  }
}

__global__ void k_cvt(const float4* __restrict__ in, u16* __restrict__ out, size_t n4) {
  size_t idx = (size_t)blockIdx.x * blockDim.x + threadIdx.x;
  const size_t stride = (size_t)gridDim.x * blockDim.x;
  for (; idx < n4; idx += stride) {
    const float4 v = in[idx];
    ushort4 o;
    o.x = f2bf(v.x); o.y = f2bf(v.y); o.z = f2bf(v.z); o.w = f2bf(v.w);
    *(ushort4*)(out + idx * 4) = o;
  }
}

__global__ void k_zero(uint4* __restrict__ p, size_t n) {
  size_t idx = (size_t)blockIdx.x * blockDim.x + threadIdx.x;
  const size_t stride = (size_t)gridDim.x * blockDim.x;
  const uint4 z = {0u, 0u, 0u, 0u};
  for (; idx < n; idx += stride) p[idx] = z;
}

// ---------------- loss ----------------
__global__ void k_loss1(const float* __restrict__ D, float* __restrict__ part) {
  __shared__ float sd[256];
  const int tid = threadIdx.x;
  float s = 0.f;
  for (int idx = blockIdx.x * 256 + tid; idx < 512 * 512; idx += 256 * 256) {
    const float x = D[idx];
    float sp;
    if (x > 20.f) sp = x;
    else if (x < -20.f) sp = __expf(x);
    else sp = __logf(1.0f + __expf(x));
    if ((idx >> 9) == (idx & 511)) sp -= x;
    s += sp;
  }
  sd[tid] = s;
  __syncthreads();
  for (int o = 128; o > 0; o >>= 1) { if (tid < o) sd[tid] += sd[tid + o]; __syncthreads(); }
  if (tid == 0) part[blockIdx.x] = sd[0];
}

__global__ void k_loss2(const float* __restrict__ part, float* __restrict__ out) {
  __shared__ float sd[256];
  const int tid = threadIdx.x;
  sd[tid] = part[tid];
  __syncthreads();
  for (int o = 128; o > 0; o >>= 1) { if (tid < o) sd[tid] += sd[tid + o]; __syncthreads(); }
  if (tid == 0) out[0] = sd[0] * (1.0f / (512.0f * 512.0f));
}

// ---------------- launch ----------------
extern "C" void kernel_launch(void* const* d_in, const int* in_sizes, int n_in,
                              void* d_out, int out_size, void* d_ws, size_t ws_size,
                              hipStream_t stream)
{
  const float* embF = (const float*)d_in[0];
  const float* W    = (const float*)d_in[1];
  const float* b    = (const float*)d_in[2];
  const float* p_i  = (const float*)d_in[3];
  const float* p_f  = (const float*)d_in[4];
  const float* p_o  = (const float*)d_in[5];
  const float* Mm   = (const float*)d_in[6];
  const int* tokQ   = (const int*)d_in[7];
  const int* tokR   = (const int*)d_in[8];
  const int* lenQ   = (const int*)d_in[9];
  const int* lenR   = (const int*)d_in[10];
  float* out = (float*)d_out;

  char* ws = (char*)d_ws;
  const size_t OFF_EMB  = 0;                       // 50000*512*2 = 51,200,000
  const size_t OFF_W2T  = 51200000;                // 4096*1536*2 = 12,582,912
  const size_t OFF_MT   = OFF_W2T + 12582912;      // 1024*1024*2 =  2,097,152
  const size_t OFF_B2   = OFF_MT + 2097152;        // 4096*4
  const size_t OFF_H    = OFF_B2 + 16384;          // 2buf*2enc*512*1024*2 = 4,194,304
  const size_t OFF_C    = OFF_H + 4194304;         // 2enc*512*1024*4 = 4,194,304
  const size_t OFF_QT   = OFF_C + 4194304;         // 512*1024*2 = 1,048,576
  const size_t OFF_PART = OFF_QT + 1048576;        // 256*4
  const size_t NEED = OFF_PART + 1024;
  if (ws_size < NEED) return;  // workspace too small: bail (output stays invalid as a signal)

  u16* embB  = (u16*)(ws + OFF_EMB);
  u16* W2T   = (u16*)(ws + OFF_W2T);
  u16* MT    = (u16*)(ws + OFF_MT);
  float* b2  = (float*)(ws + OFF_B2);
  u16* hbuf  = (u16*)(ws + OFF_H);
  float* cst = (float*)(ws + OFF_C);
  u16* qt    = (u16*)(ws + OFF_QT);
  float* part= (float*)(ws + OFF_PART);

  // prep
  k_cvt<<<dim3(2048), dim3(256), 0, stream>>>((const float4*)embF, embB, (size_t)(50000 * 512 / 4));
  k_transpose<<<dim3(64, 24), dim3(256), 0, stream>>>(W, W2T, 1536, 4096, 1);
  k_transpose<<<dim3(16, 16), dim3(256), 0, stream>>>(Mm, MT, 1024, 1024, 0);
  k_bias<<<dim3(16), dim3(256), 0, stream>>>(b, b2);
  k_zero<<<dim3(256), dim3(256), 0, stream>>>((uint4*)hbuf, 131072);   // h buf0 (2 MB)
  k_zero<<<dim3(256), dim3(256), 0, stream>>>((uint4*)cst, 262144);    // c (4 MB)

  // recurrence: h double-buffered; t reads buf (t&1), writes buf ((t+1)&1); final state in buf 0
  const size_t HBUFSTRIDE = (size_t)2 * 512 * 1024;  // u16 elems per buffer
  for (int t = 0; t < 100; ++t) {
    u16* hc = hbuf + (size_t)(t & 1) * HBUFSTRIDE;
    u16* hn = hbuf + (size_t)((t + 1) & 1) * HBUFSTRIDE;
    k_step<<<dim3(256), dim3(256), 0, stream>>>(embB, W2T, b2, p_i, p_f, p_o,
                                                tokQ, tokR, lenQ, lenR, hc, hn, cst, t);
  }

  // q_t = h_q @ M  (A = enc0 of buf0; B = M^T rows)
  k_gemm<1><<<dim3(8, 4), dim3(256), 0, stream>>>(hbuf, MT, qt, 1024, 1024);
  // distances = q_t @ h_r^T  (B rows = enc1 final h)
  k_gemm<0><<<dim3(4, 4), dim3(256), 0, stream>>>(qt, hbuf + (size_t)512 * 1024, out, 1024, 512);

  k_loss1<<<dim3(256), dim3(256), 0, stream>>>(out, part);
  k_loss2<<<dim3(1), dim3(256), 0, stream>>>(part, out + 262144);
}

// Round 4
// 2205.386 us; speedup vs baseline: 1.9860x; 1.0432x over previous
//
#include <hip/hip_runtime.h>
#include <stdint.h>

typedef unsigned short u16;
typedef __bf16 bf16x8 __attribute__((ext_vector_type(8)));
typedef float f32x4 __attribute__((ext_vector_type(4)));

#define AS1 __attribute__((address_space(1)))
#define AS3 __attribute__((address_space(3)))

__device__ __forceinline__ void ld_lds16(const void* gp, void* lp) {
  __builtin_amdgcn_global_load_lds((AS1 void*)(void*)gp, (AS3 void*)lp, 16, 0, 0);
}

__device__ __forceinline__ u16 f2bf(float f) {
  uint32_t u = __float_as_uint(f);
  u += 0x7FFFu + ((u >> 16) & 1u);
  return (u16)(u >> 16);
}

__device__ __forceinline__ float fsig(float x) { return 1.0f / (1.0f + __expf(-x)); }
__device__ __forceinline__ float ftanhf(float x) {
  float e = __expf(-2.0f * fabsf(x));
  float t = (1.0f - e) / (1.0f + e);
  return copysignf(t, x);
}

#define LSEQ 100
#define EMB 512
#define HID 1024
#define KDIM 1536

// ---------------- LSTM step: z = [x_t; h] @ W' (gates interleaved), fused gate epilogue ----------
// BK=64, 4-deep LDS pipeline (128 KB), counted vmcnt (16/8/0 — never drains in steady state),
// raw s_barrier, epilogue operands prefetched before the K-loop, XCD-swizzled blocks.
__global__ __launch_bounds__(256) void k_step(
    const u16* __restrict__ emb, const u16* __restrict__ W2T,
    const float* __restrict__ b2, const float* __restrict__ p_i,
    const float* __restrict__ p_f, const float* __restrict__ p_o,
    const int* __restrict__ tokQ, const int* __restrict__ tokR,
    const int* __restrict__ lenQ, const int* __restrict__ lenR,
    const u16* __restrict__ h_cur, u16* __restrict__ h_nxt,
    float* __restrict__ c_st, int t)
{
  __shared__ u16 sb[4 * 16384];  // 4 bufs x (lA 8192 u16 + lB 8192 u16) = 128 KB
  const int tid = threadIdx.x;
  const int lane = tid & 63, wid = tid >> 6;
  const int wm = wid >> 1, wn = wid & 1;
  const int lane_lo = lane & 15, lane_hi = lane >> 4;
  // XCD-aware swizzle: XCD k (= g%8) owns bx in {4k..4k+3}, all by.
  const int g = blockIdx.x;
  const int bx = (g & 7) * 4 + ((g >> 3) & 3);
  const int by = g >> 5;

  f32x4 acc[4][4];
  const f32x4 zz = {0.f, 0.f, 0.f, 0.f};
#pragma unroll
  for (int a = 0; a < 4; ++a)
#pragma unroll
    for (int bb = 0; bb < 4; ++bb) acc[a][bb] = zz;

  // ---- token loads FIRST (longest dependency chain); these are oldest in vmcnt order ----
  int tokv[4], rowe[4], rowi[4], ldso[4], srco[4];
#pragma unroll
  for (int j = 0; j < 4; ++j) {
    const int cbase = (j * 4 + wid) * 64;   // chunk base; 8 chunks (128 B) per row
    const int ch = cbase + lane;
    const int r = ch >> 3;
    const int srcoff = ((((ch & 7) << 4) ^ ((r & 7) << 4)) >> 1);  // R2 zero-conflict swizzle
    const int m = by * 128 + r, e = m >> 9, i = m & 511;
    tokv[j] = (e ? tokR : tokQ)[i * LSEQ + t];
    rowe[j] = e; rowi[j] = i;
    srco[j] = srcoff;
    ldso[j] = cbase * 8;  // u16 elems (8 per 16 B chunk)
  }

  // ---- epilogue operand prefetch (issued BEFORE stages: oldest in vmcnt, hidden under K-loop) ----
  const int colbase = bx * 128 + wn * 64;
  const int h = ((colbase >> 6) << 4) + lane_lo;
  float b2v[4];
#pragma unroll
  for (int gg = 0; gg < 4; ++gg) b2v[gg] = b2[colbase + gg * 16 + lane_lo];
  const float pi = p_i[h], pf = p_f[h], po = p_o[h];
  int lenv[4][4];
  float cold[4][4];
  u16 hprev[4][4];
#pragma unroll
  for (int mi = 0; mi < 4; ++mi)
#pragma unroll
    for (int r = 0; r < 4; ++r) {
      const int m = by * 128 + wm * 64 + mi * 16 + lane_hi * 4 + r;
      const int e = m >> 9, i = m & 511;
      lenv[mi][r] = e ? lenR[i] : lenQ[i];
      const size_t ci = (size_t)(e * 512 + i) * HID + h;
      cold[mi][r] = c_st[ci];
      hprev[mi][r] = h_cur[ci];
    }
  __builtin_amdgcn_sched_barrier(0);  // pin: all prologue vmem issued before stage 0

  // ---- staging pointers ----
  const u16* pAx[4];
  const u16* pAh[4];
  const u16* pB[4];
#pragma unroll
  for (int j = 0; j < 4; ++j) {
    const int cbase = (j * 4 + wid) * 64;
    const int r = (cbase + lane) >> 3;
    pAx[j] = emb + (size_t)tokv[j] * EMB + srco[j];
    pAh[j] = h_cur + (size_t)(rowe[j] * 512 + rowi[j]) * HID - 512 + srco[j];  // kb>=512 when used
    pB[j]  = W2T + (size_t)(bx * 128 + r) * KDIM + srco[j];
  }

  auto stage = [&](int kt, int buf) {
    const int kb = kt * 64;
    u16* lA = sb + buf * 16384;
    u16* lB = lA + 8192;
    const bool isx = kb < EMB;  // uniform per kt
#pragma unroll
    for (int j = 0; j < 4; ++j) ld_lds16((isx ? pAx[j] : pAh[j]) + kb, lA + ldso[j]);
#pragma unroll
    for (int j = 0; j < 4; ++j) ld_lds16(pB[j] + kb, lB + ldso[j]);
  };

  auto compute = [&](int buf) {
    const u16* lA = sb + buf * 16384;
    const u16* lB = lA + 8192;
#pragma unroll
    for (int kk = 0; kk < 2; ++kk) {
      bf16x8 aF[4], bF[4];
#pragma unroll
      for (int mi = 0; mi < 4; ++mi) {
        const int rr = wm * 64 + mi * 16 + lane_lo;
        const int byo = rr * 128 + ((kk * 64 + lane_hi * 16) ^ ((rr & 7) << 4));
        aF[mi] = *(const bf16x8*)((const char*)lA + byo);
      }
#pragma unroll
      for (int ni = 0; ni < 4; ++ni) {
        const int rr = wn * 64 + ni * 16 + lane_lo;
        const int byo = rr * 128 + ((kk * 64 + lane_hi * 16) ^ ((rr & 7) << 4));
        bF[ni] = *(const bf16x8*)((const char*)lB + byo);
      }
#pragma unroll
      for (int mi = 0; mi < 4; ++mi)
#pragma unroll
        for (int ni = 0; ni < 4; ++ni)
          acc[mi][ni] = __builtin_amdgcn_mfma_f32_16x16x32_bf16(aF[mi], bF[ni], acc[mi][ni], 0, 0, 0);
    }
  };

  // ---- prologue: fill 3 stages (8 loads/wave each; 24 outstanding) ----
  stage(0, 0);
  stage(1, 1);
  stage(2, 2);

  // ---- K loop: 24 iters. wait own stage-kt (counted!), barrier, prefetch kt+3, compute kt ----
  for (int kt = 0; kt < 24; ++kt) {
    if (kt <= 21)      asm volatile("s_waitcnt vmcnt(16)" ::: "memory");
    else if (kt == 22) asm volatile("s_waitcnt vmcnt(8)" ::: "memory");
    else               asm volatile("s_waitcnt vmcnt(0)" ::: "memory");
    __builtin_amdgcn_s_barrier();
    __builtin_amdgcn_sched_barrier(0);
    if (kt < 21) stage(kt + 3, (kt + 3) & 3);
    __builtin_amdgcn_s_setprio(1);
    compute(kt & 3);
    __builtin_amdgcn_s_setprio(0);
  }

  // ----- fused gate epilogue: lane owns one h, 16 rows; ni == gate index -----
#pragma unroll
  for (int mi = 0; mi < 4; ++mi) {
#pragma unroll
    for (int r = 0; r < 4; ++r) {
      const int m = by * 128 + wm * 64 + mi * 16 + lane_hi * 4 + r;
      const int e = m >> 9, i = m & 511;
      const size_t ci = (size_t)(e * 512 + i) * HID + h;
      u16 hv;
      if (t < lenv[mi][r]) {
        const float c_old = cold[mi][r];
        const float zi = acc[mi][0][r] + b2v[0] + pi * c_old;
        const float zj = acc[mi][1][r] + b2v[1];
        const float zf = acc[mi][2][r] + b2v[2] + pf * c_old;  // FORGET_BIAS folded into b2
        const float zo = acc[mi][3][r] + b2v[3];
        const float ig = fsig(zi), fg = fsig(zf);
        const float cn = fg * c_old + ig * ftanhf(zj);
        const float og = fsig(zo + po * cn);
        const float hn = og * ftanhf(cn);
        c_st[ci] = cn;
        hv = f2bf(hn);
      } else {
        hv = hprev[mi][r];
      }
      h_nxt[ci] = hv;
    }
  }
}

// ---------------- generic bf16 GEMM: C[m][n] = sum_k A[m][k] * Bn[n][k] ----------------
template <int OUT_BF16>
__global__ __launch_bounds__(256) void k_gemm(
    const u16* __restrict__ A, const u16* __restrict__ Bn,
    void* __restrict__ Cout, int K, int ldc)
{
  __shared__ u16 lA[128 * 64];
  __shared__ u16 lB[128 * 64];
  const int tid = threadIdx.x;
  const int lane = tid & 63, wid = tid >> 6;
  const int wm = wid >> 1, wn = wid & 1;
  const int lane_lo = lane & 15, lane_hi = lane >> 4;
  const int bx = blockIdx.x, by = blockIdx.y;

  f32x4 acc[4][4];
  const f32x4 zz = {0.f, 0.f, 0.f, 0.f};
#pragma unroll
  for (int a = 0; a < 4; ++a)
#pragma unroll
    for (int bb = 0; bb < 4; ++bb) acc[a][bb] = zz;

  const int nkt = K >> 6;
  for (int kt = 0; kt < nkt; ++kt) {
    const int kb = kt * 64;
#pragma unroll
    for (int j = 0; j < 4; ++j) {
      const int cbase = (j * 4 + wid) * 64;
      const int ch = cbase + lane;
      const int r = ch >> 3;
      const int srcoff = ((((ch & 7) << 4) ^ ((r & 7) << 4)) >> 1);
      ld_lds16(A + (size_t)(by * 128 + r) * K + kb + srcoff, &lA[cbase * 8]);
    }
#pragma unroll
    for (int j = 0; j < 4; ++j) {
      const int cbase = (j * 4 + wid) * 64;
      const int ch = cbase + lane;
      const int r = ch >> 3;
      const int srcoff = ((((ch & 7) << 4) ^ ((r & 7) << 4)) >> 1);
      ld_lds16(Bn + (size_t)(bx * 128 + r) * K + kb + srcoff, &lB[cbase * 8]);
    }
    __syncthreads();
#pragma unroll
    for (int kk = 0; kk < 2; ++kk) {
      bf16x8 aF[4], bF[4];
#pragma unroll
      for (int mi = 0; mi < 4; ++mi) {
        const int rr = wm * 64 + mi * 16 + lane_lo;
        const int byo = rr * 128 + ((kk * 64 + lane_hi * 16) ^ ((rr & 7) << 4));
        aF[mi] = *(const bf16x8*)((const char*)lA + byo);
      }
#pragma unroll
      for (int ni = 0; ni < 4; ++ni) {
        const int rr = wn * 64 + ni * 16 + lane_lo;
        const int byo = rr * 128 + ((kk * 64 + lane_hi * 16) ^ ((rr & 7) << 4));
        bF[ni] = *(const bf16x8*)((const char*)lB + byo);
      }
#pragma unroll
      for (int mi = 0; mi < 4; ++mi)
#pragma unroll
        for (int ni = 0; ni < 4; ++ni)
          acc[mi][ni] = __builtin_amdgcn_mfma_f32_16x16x32_bf16(aF[mi], bF[ni], acc[mi][ni], 0, 0, 0);
    }
    __syncthreads();
  }

#pragma unroll
  for (int mi = 0; mi < 4; ++mi)
#pragma unroll
    for (int r = 0; r < 4; ++r) {
      const int m = by * 128 + wm * 64 + mi * 16 + lane_hi * 4 + r;
#pragma unroll
      for (int ni = 0; ni < 4; ++ni) {
        const int col = bx * 128 + wn * 64 + ni * 16 + lane_lo;
        const float v = acc[mi][ni][r];
        if (OUT_BF16) ((u16*)Cout)[(size_t)m * ldc + col] = f2bf(v);
        else ((float*)Cout)[(size_t)m * ldc + col] = v;
      }
    }
}

// ---------------- prep kernels ----------------
// out[n'][k] (bf16) = in[k][n] (f32); perm!=0 applies gate-interleave permutation (N_=4096)
__global__ void k_transpose(const float* __restrict__ in, u16* __restrict__ out,
                            int K_, int N_, int perm)
{
  __shared__ float tile[64][65];
  const int tid = threadIdx.x;
  const int k0 = blockIdx.y * 64, n0 = blockIdx.x * 64;
  const int c = tid & 63, rq = tid >> 6;
  for (int rr = 0; rr < 64; rr += 4)
    tile[rr + rq][c] = in[(size_t)(k0 + rr + rq) * N_ + n0 + c];
  __syncthreads();
  for (int nr0 = 0; nr0 < 64; nr0 += 4) {
    const int nr = nr0 + rq;
    const int n = n0 + nr;
    int np = n;
    if (perm) {
      const int g = n >> 10, hh = n & 1023;
      np = ((hh >> 4) << 6) + (g << 4) + (hh & 15);
    }
    out[(size_t)np * K_ + k0 + c] = f2bf(tile[c][nr]);
  }
}

__global__ void k_bias(const float* __restrict__ b, float* __restrict__ b2) {
  const int n = blockIdx.x * 256 + threadIdx.x;
  if (n < 4096) {
    const int g = n >> 10, hh = n & 1023;
    const int np = ((hh >> 4) << 6) + (g << 4) + (hh & 15);
    b2[np] = b[n] + (g == 2 ? 2.0f : 0.0f);
  }
}

__global__ void k_cvt(const float4* __restrict__ in, u16* __restrict__ out, size_t n4) {
  size_t idx = (size_t)blockIdx.x * blockDim.x + threadIdx.x;
  const size_t stride = (size_t)gridDim.x * blockDim.x;
  for (; idx < n4; idx += stride) {
    const float4 v = in[idx];
    ushort4 o;
    o.x = f2bf(v.x); o.y = f2bf(v.y); o.z = f2bf(v.z); o.w = f2bf(v.w);
    *(ushort4*)(out + idx * 4) = o;
  }
}

__global__ void k_zero(uint4* __restrict__ p, size_t n) {
  size_t idx = (size_t)blockIdx.x * blockDim.x + threadIdx.x;
  const size_t stride = (size_t)gridDim.x * blockDim.x;
  const uint4 z = {0u, 0u, 0u, 0u};
  for (; idx < n; idx += stride) p[idx] = z;
}

// ---------------- loss ----------------
__global__ void k_loss1(const float* __restrict__ D, float* __restrict__ part) {
  __shared__ float sd[256];
  const int tid = threadIdx.x;
  float s = 0.f;
  for (int idx = blockIdx.x * 256 + tid; idx < 512 * 512; idx += 256 * 256) {
    const float x = D[idx];
    float sp;
    if (x > 20.f) sp = x;
    else if (x < -20.f) sp = __expf(x);
    else sp = __logf(1.0f + __expf(x));
    if ((idx >> 9) == (idx & 511)) sp -= x;
    s += sp;
  }
  sd[tid] = s;
  __syncthreads();
  for (int o = 128; o > 0; o >>= 1) { if (tid < o) sd[tid] += sd[tid + o]; __syncthreads(); }
  if (tid == 0) part[blockIdx.x] = sd[0];
}

__global__ void k_loss2(const float* __restrict__ part, float* __restrict__ out) {
  __shared__ float sd[256];
  const int tid = threadIdx.x;
  sd[tid] = part[tid];
  __syncthreads();
  for (int o = 128; o > 0; o >>= 1) { if (tid < o) sd[tid] += sd[tid + o]; __syncthreads(); }
  if (tid == 0) out[0] = sd[0] * (1.0f / (512.0f * 512.0f));
}

// ---------------- launch ----------------
extern "C" void kernel_launch(void* const* d_in, const int* in_sizes, int n_in,
                              void* d_out, int out_size, void* d_ws, size_t ws_size,
                              hipStream_t stream)
{
  const float* embF = (const float*)d_in[0];
  const float* W    = (const float*)d_in[1];
  const float* b    = (const float*)d_in[2];
  const float* p_i  = (const float*)d_in[3];
  const float* p_f  = (const float*)d_in[4];
  const float* p_o  = (const float*)d_in[5];
  const float* Mm   = (const float*)d_in[6];
  const int* tokQ   = (const int*)d_in[7];
  const int* tokR   = (const int*)d_in[8];
  const int* lenQ   = (const int*)d_in[9];
  const int* lenR   = (const int*)d_in[10];
  float* out = (float*)d_out;

  char* ws = (char*)d_ws;
  const size_t OFF_EMB  = 0;                       // 50000*512*2 = 51,200,000
  const size_t OFF_W2T  = 51200000;                // 4096*1536*2 = 12,582,912
  const size_t OFF_MT   = OFF_W2T + 12582912;      // 1024*1024*2 =  2,097,152
  const size_t OFF_B2   = OFF_MT + 2097152;        // 4096*4
  const size_t OFF_H    = OFF_B2 + 16384;          // 2buf*2enc*512*1024*2 = 4,194,304
  const size_t OFF_C    = OFF_H + 4194304;         // 2enc*512*1024*4 = 4,194,304
  const size_t OFF_QT   = OFF_C + 4194304;         // 512*1024*2 = 1,048,576
  const size_t OFF_PART = OFF_QT + 1048576;        // 256*4
  const size_t NEED = OFF_PART + 1024;
  if (ws_size < NEED) return;  // workspace too small: bail (output stays invalid as a signal)

  u16* embB  = (u16*)(ws + OFF_EMB);
  u16* W2T   = (u16*)(ws + OFF_W2T);
  u16* MT    = (u16*)(ws + OFF_MT);
  float* b2  = (float*)(ws + OFF_B2);
  u16* hbuf  = (u16*)(ws + OFF_H);
  float* cst = (float*)(ws + OFF_C);
  u16* qt    = (u16*)(ws + OFF_QT);
  float* part= (float*)(ws + OFF_PART);

  // prep
  k_cvt<<<dim3(2048), dim3(256), 0, stream>>>((const float4*)embF, embB, (size_t)(50000 * 512 / 4));
  k_transpose<<<dim3(64, 24), dim3(256), 0, stream>>>(W, W2T, 1536, 4096, 1);
  k_transpose<<<dim3(16, 16), dim3(256), 0, stream>>>(Mm, MT, 1024, 1024, 0);
  k_bias<<<dim3(16), dim3(256), 0, stream>>>(b, b2);
  k_zero<<<dim3(256), dim3(256), 0, stream>>>((uint4*)hbuf, 131072);   // h buf0 (2 MB)
  k_zero<<<dim3(256), dim3(256), 0, stream>>>((uint4*)cst, 262144);    // c (4 MB)

  // recurrence: h double-buffered; t reads buf (t&1), writes buf ((t+1)&1); final state in buf 0
  const size_t HBUFSTRIDE = (size_t)2 * 512 * 1024;  // u16 elems per buffer
  for (int t = 0; t < 100; ++t) {
    u16* hc = hbuf + (size_t)(t & 1) * HBUFSTRIDE;
    u16* hn = hbuf + (size_t)((t + 1) & 1) * HBUFSTRIDE;
    k_step<<<dim3(256), dim3(256), 0, stream>>>(embB, W2T, b2, p_i, p_f, p_o,
                                                tokQ, tokR, lenQ, lenR, hc, hn, cst, t);
  }

  // q_t = h_q @ M  (A = enc0 of buf0; B = M^T rows)
  k_gemm<1><<<dim3(8, 4), dim3(256), 0, stream>>>(hbuf, MT, qt, 1024, 1024);
  // distances = q_t @ h_r^T  (B rows = enc1 final h)
  k_gemm<0><<<dim3(4, 4), dim3(256), 0, stream>>>(qt, hbuf + (size_t)512 * 1024, out, 1024, 512);

  k_loss1<<<dim3(256), dim3(256), 0, stream>>>(out, part);
  k_loss2<<<dim3(1), dim3(256), 0, stream>>>(part, out + 262144);
}

// Round 5
// 2061.049 us; speedup vs baseline: 2.1251x; 1.0700x over previous
//
#include <hip/hip_runtime.h>
#include <stdint.h>

typedef unsigned short u16;
typedef __bf16 bf16x8 __attribute__((ext_vector_type(8)));
typedef float f32x4 __attribute__((ext_vector_type(4)));

#define AS1 __attribute__((address_space(1)))
#define AS3 __attribute__((address_space(3)))

__device__ __forceinline__ void ld_lds16(const void* gp, void* lp) {
  __builtin_amdgcn_global_load_lds((AS1 void*)(void*)gp, (AS3 void*)lp, 16, 0, 0);
}

__device__ __forceinline__ u16 f2bf(float f) {
  uint32_t u = __float_as_uint(f);
  u += 0x7FFFu + ((u >> 16) & 1u);
  return (u16)(u >> 16);
}

__device__ __forceinline__ float fsig(float x) { return 1.0f / (1.0f + __expf(-x)); }
__device__ __forceinline__ float ftanhf(float x) {
  float e = __expf(-2.0f * fabsf(x));
  float t = (1.0f - e) / (1.0f + e);
  return copysignf(t, x);
}

#define LSEQ 100
#define EMB 512
#define HID 1024
#define KDIM 1536

// ---------------- LSTM step: z = [x_t; h] @ W' (gates interleaved), fused gate epilogue ----------
// 512 threads (8 waves = 4m x 2n, wave tile 32x64) -> 2 waves/SIMD for latency hiding.
// BK=64, 4-deep LDS pipeline (128 KB), counted vmcnt (8/4/0), raw s_barrier,
// epilogue operands prefetched before the K-loop, XCD-swizzled blocks.
__global__ __launch_bounds__(512, 2) void k_step(
    const u16* __restrict__ emb, const u16* __restrict__ W2T,
    const float* __restrict__ b2, const float* __restrict__ p_i,
    const float* __restrict__ p_f, const float* __restrict__ p_o,
    const int* __restrict__ tokQ, const int* __restrict__ tokR,
    const int* __restrict__ lenQ, const int* __restrict__ lenR,
    const u16* __restrict__ h_cur, u16* __restrict__ h_nxt,
    float* __restrict__ c_st, int t)
{
  __shared__ u16 sb[4 * 16384];  // 4 bufs x (lA 8192 u16 + lB 8192 u16) = 128 KB
  const int tid = threadIdx.x;
  const int lane = tid & 63, wid = tid >> 6;       // 8 waves
  const int wm = wid >> 1, wn = wid & 1;           // 4m x 2n; wave tile 32 rows x 64 cols
  const int lane_lo = lane & 15, lane_hi = lane >> 4;
  // XCD-aware swizzle: XCD k (= g%8) owns bx in {4k..4k+3}, all by.
  const int g = blockIdx.x;
  const int bx = (g & 7) * 4 + ((g >> 3) & 3);
  const int by = g >> 5;

  f32x4 acc[2][4];
  const f32x4 zz = {0.f, 0.f, 0.f, 0.f};
#pragma unroll
  for (int a = 0; a < 2; ++a)
#pragma unroll
    for (int bb = 0; bb < 4; ++bb) acc[a][bb] = zz;

  // ---- token loads FIRST (longest dependency chain) ----
  int tokv[2], rowe[2], rowi[2], ldso[2], srco[2];
#pragma unroll
  for (int j = 0; j < 2; ++j) {
    const int cbase = (j * 8 + wid) * 64;   // chunk base; 8 chunks (128 B) per row
    const int ch = cbase + lane;
    const int r = ch >> 3;
    const int srcoff = ((((ch & 7) << 4) ^ ((r & 7) << 4)) >> 1);  // zero-conflict swizzle
    const int m = by * 128 + r, e = m >> 9, i = m & 511;
    tokv[j] = (e ? tokR : tokQ)[i * LSEQ + t];
    rowe[j] = e; rowi[j] = i;
    srco[j] = srcoff;
    ldso[j] = cbase * 8;  // u16 elems (8 per 16 B chunk)
  }

  // ---- epilogue operand prefetch (oldest in vmcnt, hidden under K-loop) ----
  const int colbase = bx * 128 + wn * 64;
  const int h = ((colbase >> 6) << 4) + lane_lo;
  float b2v[4];
#pragma unroll
  for (int gg = 0; gg < 4; ++gg) b2v[gg] = b2[colbase + gg * 16 + lane_lo];
  const float pi = p_i[h], pf = p_f[h], po = p_o[h];
  int lenv[2][4];
  float cold[2][4];
  u16 hprev[2][4];
#pragma unroll
  for (int mi = 0; mi < 2; ++mi)
#pragma unroll
    for (int r = 0; r < 4; ++r) {
      const int m = by * 128 + wm * 32 + mi * 16 + lane_hi * 4 + r;
      const int e = m >> 9, i = m & 511;
      lenv[mi][r] = e ? lenR[i] : lenQ[i];
      const size_t ci = (size_t)(e * 512 + i) * HID + h;
      cold[mi][r] = c_st[ci];
      hprev[mi][r] = h_cur[ci];
    }
  __builtin_amdgcn_sched_barrier(0);  // pin: all prologue vmem issued before stage 0

  // ---- staging pointers ----
  const u16* pAx[2];
  const u16* pAh[2];
  const u16* pB[2];
#pragma unroll
  for (int j = 0; j < 2; ++j) {
    const int cbase = (j * 8 + wid) * 64;
    const int r = (cbase + lane) >> 3;
    pAx[j] = emb + (size_t)tokv[j] * EMB + srco[j];
    pAh[j] = h_cur + (size_t)(rowe[j] * 512 + rowi[j]) * HID - 512 + srco[j];  // kb>=512 when used
    pB[j]  = W2T + (size_t)(bx * 128 + r) * KDIM + srco[j];
  }

  auto stage = [&](int kt, int buf) {
    const int kb = kt * 64;
    u16* lA = sb + buf * 16384;
    u16* lB = lA + 8192;
    const bool isx = kb < EMB;  // uniform per kt
#pragma unroll
    for (int j = 0; j < 2; ++j) ld_lds16((isx ? pAx[j] : pAh[j]) + kb, lA + ldso[j]);
#pragma unroll
    for (int j = 0; j < 2; ++j) ld_lds16(pB[j] + kb, lB + ldso[j]);
  };

  auto compute = [&](int buf) {
    const u16* lA = sb + buf * 16384;
    const u16* lB = lA + 8192;
#pragma unroll
    for (int kk = 0; kk < 2; ++kk) {
      bf16x8 aF[2], bF[4];
#pragma unroll
      for (int mi = 0; mi < 2; ++mi) {
        const int rr = wm * 32 + mi * 16 + lane_lo;
        const int byo = rr * 128 + ((kk * 64 + lane_hi * 16) ^ ((rr & 7) << 4));
        aF[mi] = *(const bf16x8*)((const char*)lA + byo);
      }
#pragma unroll
      for (int ni = 0; ni < 4; ++ni) {
        const int rr = wn * 64 + ni * 16 + lane_lo;
        const int byo = rr * 128 + ((kk * 64 + lane_hi * 16) ^ ((rr & 7) << 4));
        bF[ni] = *(const bf16x8*)((const char*)lB + byo);
      }
#pragma unroll
      for (int mi = 0; mi < 2; ++mi)
#pragma unroll
        for (int ni = 0; ni < 4; ++ni)
          acc[mi][ni] = __builtin_amdgcn_mfma_f32_16x16x32_bf16(aF[mi], bF[ni], acc[mi][ni], 0, 0, 0);
    }
  };

  // ---- prologue: fill 3 stages (4 loads/thread each; 12 outstanding) ----
  stage(0, 0);
  stage(1, 1);
  stage(2, 2);

  // ---- K loop: 24 iters. wait own stage-kt (counted!), barrier, prefetch kt+3, compute kt ----
  for (int kt = 0; kt < 24; ++kt) {
    if (kt <= 21)      asm volatile("s_waitcnt vmcnt(8)" ::: "memory");
    else if (kt == 22) asm volatile("s_waitcnt vmcnt(4)" ::: "memory");
    else               asm volatile("s_waitcnt vmcnt(0)" ::: "memory");
    __builtin_amdgcn_s_barrier();
    __builtin_amdgcn_sched_barrier(0);
    if (kt < 21) stage(kt + 3, (kt + 3) & 3);
    __builtin_amdgcn_s_setprio(1);
    compute(kt & 3);
    __builtin_amdgcn_s_setprio(0);
  }

  // ----- fused gate epilogue: lane owns one h, 8 rows; ni == gate index -----
#pragma unroll
  for (int mi = 0; mi < 2; ++mi) {
#pragma unroll
    for (int r = 0; r < 4; ++r) {
      const int m = by * 128 + wm * 32 + mi * 16 + lane_hi * 4 + r;
      const int e = m >> 9, i = m & 511;
      const size_t ci = (size_t)(e * 512 + i) * HID + h;
      u16 hv;
      if (t < lenv[mi][r]) {
        const float c_old = cold[mi][r];
        const float zi = acc[mi][0][r] + b2v[0] + pi * c_old;
        const float zj = acc[mi][1][r] + b2v[1];
        const float zf = acc[mi][2][r] + b2v[2] + pf * c_old;  // FORGET_BIAS folded into b2
        const float zo = acc[mi][3][r] + b2v[3];
        const float ig = fsig(zi), fg = fsig(zf);
        const float cn = fg * c_old + ig * ftanhf(zj);
        const float og = fsig(zo + po * cn);
        const float hn = og * ftanhf(cn);
        c_st[ci] = cn;
        hv = f2bf(hn);
      } else {
        hv = hprev[mi][r];
      }
      h_nxt[ci] = hv;
    }
  }
}

// ---------------- generic bf16 GEMM: C[m][n] = sum_k A[m][k] * Bn[n][k] ----------------
template <int OUT_BF16>
__global__ __launch_bounds__(256) void k_gemm(
    const u16* __restrict__ A, const u16* __restrict__ Bn,
    void* __restrict__ Cout, int K, int ldc)
{
  __shared__ u16 lA[128 * 64];
  __shared__ u16 lB[128 * 64];
  const int tid = threadIdx.x;
  const int lane = tid & 63, wid = tid >> 6;
  const int wm = wid >> 1, wn = wid & 1;
  const int lane_lo = lane & 15, lane_hi = lane >> 4;
  const int bx = blockIdx.x, by = blockIdx.y;

  f32x4 acc[4][4];
  const f32x4 zz = {0.f, 0.f, 0.f, 0.f};
#pragma unroll
  for (int a = 0; a < 4; ++a)
#pragma unroll
    for (int bb = 0; bb < 4; ++bb) acc[a][bb] = zz;

  const int nkt = K >> 6;
  for (int kt = 0; kt < nkt; ++kt) {
    const int kb = kt * 64;
#pragma unroll
    for (int j = 0; j < 4; ++j) {
      const int cbase = (j * 4 + wid) * 64;
      const int ch = cbase + lane;
      const int r = ch >> 3;
      const int srcoff = ((((ch & 7) << 4) ^ ((r & 7) << 4)) >> 1);
      ld_lds16(A + (size_t)(by * 128 + r) * K + kb + srcoff, &lA[cbase * 8]);
    }
#pragma unroll
    for (int j = 0; j < 4; ++j) {
      const int cbase = (j * 4 + wid) * 64;
      const int ch = cbase + lane;
      const int r = ch >> 3;
      const int srcoff = ((((ch & 7) << 4) ^ ((r & 7) << 4)) >> 1);
      ld_lds16(Bn + (size_t)(bx * 128 + r) * K + kb + srcoff, &lB[cbase * 8]);
    }
    __syncthreads();
#pragma unroll
    for (int kk = 0; kk < 2; ++kk) {
      bf16x8 aF[4], bF[4];
#pragma unroll
      for (int mi = 0; mi < 4; ++mi) {
        const int rr = wm * 64 + mi * 16 + lane_lo;
        const int byo = rr * 128 + ((kk * 64 + lane_hi * 16) ^ ((rr & 7) << 4));
        aF[mi] = *(const bf16x8*)((const char*)lA + byo);
      }
#pragma unroll
      for (int ni = 0; ni < 4; ++ni) {
        const int rr = wn * 64 + ni * 16 + lane_lo;
        const int byo = rr * 128 + ((kk * 64 + lane_hi * 16) ^ ((rr & 7) << 4));
        bF[ni] = *(const bf16x8*)((const char*)lB + byo);
      }
#pragma unroll
      for (int mi = 0; mi < 4; ++mi)
#pragma unroll
        for (int ni = 0; ni < 4; ++ni)
          acc[mi][ni] = __builtin_amdgcn_mfma_f32_16x16x32_bf16(aF[mi], bF[ni], acc[mi][ni], 0, 0, 0);
    }
    __syncthreads();
  }

#pragma unroll
  for (int mi = 0; mi < 4; ++mi)
#pragma unroll
    for (int r = 0; r < 4; ++r) {
      const int m = by * 128 + wm * 64 + mi * 16 + lane_hi * 4 + r;
#pragma unroll
      for (int ni = 0; ni < 4; ++ni) {
        const int col = bx * 128 + wn * 64 + ni * 16 + lane_lo;
        const float v = acc[mi][ni][r];
        if (OUT_BF16) ((u16*)Cout)[(size_t)m * ldc + col] = f2bf(v);
        else ((float*)Cout)[(size_t)m * ldc + col] = v;
      }
    }
}

// ---------------- prep kernels ----------------
// out[n'][k] (bf16) = in[k][n] (f32); perm!=0 applies gate-interleave permutation (N_=4096)
__global__ void k_transpose(const float* __restrict__ in, u16* __restrict__ out,
                            int K_, int N_, int perm)
{
  __shared__ float tile[64][65];
  const int tid = threadIdx.x;
  const int k0 = blockIdx.y * 64, n0 = blockIdx.x * 64;
  const int c = tid & 63, rq = tid >> 6;
  for (int rr = 0; rr < 64; rr += 4)
    tile[rr + rq][c] = in[(size_t)(k0 + rr + rq) * N_ + n0 + c];
  __syncthreads();
  for (int nr0 = 0; nr0 < 64; nr0 += 4) {
    const int nr = nr0 + rq;
    const int n = n0 + nr;
    int np = n;
    if (perm) {
      const int g = n >> 10, hh = n & 1023;
      np = ((hh >> 4) << 6) + (g << 4) + (hh & 15);
    }
    out[(size_t)np * K_ + k0 + c] = f2bf(tile[c][nr]);
  }
}

__global__ void k_bias(const float* __restrict__ b, float* __restrict__ b2) {
  const int n = blockIdx.x * 256 + threadIdx.x;
  if (n < 4096) {
    const int g = n >> 10, hh = n & 1023;
    const int np = ((hh >> 4) << 6) + (g << 4) + (hh & 15);
    b2[np] = b[n] + (g == 2 ? 2.0f : 0.0f);
  }
}

__global__ void k_cvt(const float4* __restrict__ in, u16* __restrict__ out, size_t n4) {
  size_t idx = (size_t)blockIdx.x * blockDim.x + threadIdx.x;
  const size_t stride = (size_t)gridDim.x * blockDim.x;
  for (; idx < n4; idx += stride) {
    const float4 v = in[idx];
    ushort4 o;
    o.x = f2bf(v.x); o.y = f2bf(v.y); o.z = f2bf(v.z); o.w = f2bf(v.w);
    *(ushort4*)(out + idx * 4) = o;
  }
}

__global__ void k_zero(uint4* __restrict__ p, size_t n) {
  size_t idx = (size_t)blockIdx.x * blockDim.x + threadIdx.x;
  const size_t stride = (size_t)gridDim.x * blockDim.x;
  const uint4 z = {0u, 0u, 0u, 0u};
  for (; idx < n; idx += stride) p[idx] = z;
}

// ---------------- loss ----------------
__global__ void k_loss1(const float* __restrict__ D, float* __restrict__ part) {
  __shared__ float sd[256];
  const int tid = threadIdx.x;
  float s = 0.f;
  for (int idx = blockIdx.x * 256 + tid; idx < 512 * 512; idx += 256 * 256) {
    const float x = D[idx];
    float sp;
    if (x > 20.f) sp = x;
    else if (x < -20.f) sp = __expf(x);
    else sp = __logf(1.0f + __expf(x));
    if ((idx >> 9) == (idx & 511)) sp -= x;
    s += sp;
  }
  sd[tid] = s;
  __syncthreads();
  for (int o = 128; o > 0; o >>= 1) { if (tid < o) sd[tid] += sd[tid + o]; __syncthreads(); }
  if (tid == 0) part[blockIdx.x] = sd[0];
}

__global__ void k_loss2(const float* __restrict__ part, float* __restrict__ out) {
  __shared__ float sd[256];
  const int tid = threadIdx.x;
  sd[tid] = part[tid];
  __syncthreads();
  for (int o = 128; o > 0; o >>= 1) { if (tid < o) sd[tid] += sd[tid + o]; __syncthreads(); }
  if (tid == 0) out[0] = sd[0] * (1.0f / (512.0f * 512.0f));
}

// ---------------- launch ----------------
extern "C" void kernel_launch(void* const* d_in, const int* in_sizes, int n_in,
                              void* d_out, int out_size, void* d_ws, size_t ws_size,
                              hipStream_t stream)
{
  const float* embF = (const float*)d_in[0];
  const float* W    = (const float*)d_in[1];
  const float* b    = (const float*)d_in[2];
  const float* p_i  = (const float*)d_in[3];
  const float* p_f  = (const float*)d_in[4];
  const float* p_o  = (const float*)d_in[5];
  const float* Mm   = (const float*)d_in[6];
  const int* tokQ   = (const int*)d_in[7];
  const int* tokR   = (const int*)d_in[8];
  const int* lenQ   = (const int*)d_in[9];
  const int* lenR   = (const int*)d_in[10];
  float* out = (float*)d_out;

  char* ws = (char*)d_ws;
  const size_t OFF_EMB  = 0;                       // 50000*512*2 = 51,200,000
  const size_t OFF_W2T  = 51200000;                // 4096*1536*2 = 12,582,912
  const size_t OFF_MT   = OFF_W2T + 12582912;      // 1024*1024*2 =  2,097,152
  const size_t OFF_B2   = OFF_MT + 2097152;        // 4096*4
  const size_t OFF_H    = OFF_B2 + 16384;          // 2buf*2enc*512*1024*2 = 4,194,304
  const size_t OFF_C    = OFF_H + 4194304;         // 2enc*512*1024*4 = 4,194,304
  const size_t OFF_QT   = OFF_C + 4194304;         // 512*1024*2 = 1,048,576
  const size_t OFF_PART = OFF_QT + 1048576;        // 256*4
  const size_t NEED = OFF_PART + 1024;
  if (ws_size < NEED) return;  // workspace too small: bail (output stays invalid as a signal)

  u16* embB  = (u16*)(ws + OFF_EMB);
  u16* W2T   = (u16*)(ws + OFF_W2T);
  u16* MT    = (u16*)(ws + OFF_MT);
  float* b2  = (float*)(ws + OFF_B2);
  u16* hbuf  = (u16*)(ws + OFF_H);
  float* cst = (float*)(ws + OFF_C);
  u16* qt    = (u16*)(ws + OFF_QT);
  float* part= (float*)(ws + OFF_PART);

  // prep
  k_cvt<<<dim3(2048), dim3(256), 0, stream>>>((const float4*)embF, embB, (size_t)(50000 * 512 / 4));
  k_transpose<<<dim3(64, 24), dim3(256), 0, stream>>>(W, W2T, 1536, 4096, 1);
  k_transpose<<<dim3(16, 16), dim3(256), 0, stream>>>(Mm, MT, 1024, 1024, 0);
  k_bias<<<dim3(16), dim3(256), 0, stream>>>(b, b2);
  k_zero<<<dim3(256), dim3(256), 0, stream>>>((uint4*)hbuf, 131072);   // h buf0 (2 MB)
  k_zero<<<dim3(256), dim3(256), 0, stream>>>((uint4*)cst, 262144);    // c (4 MB)

  // recurrence: h double-buffered; t reads buf (t&1), writes buf ((t+1)&1); final state in buf 0
  const size_t HBUFSTRIDE = (size_t)2 * 512 * 1024;  // u16 elems per buffer
  for (int t = 0; t < 100; ++t) {
    u16* hc = hbuf + (size_t)(t & 1) * HBUFSTRIDE;
    u16* hn = hbuf + (size_t)((t + 1) & 1) * HBUFSTRIDE;
    k_step<<<dim3(256), dim3(512), 0, stream>>>(embB, W2T, b2, p_i, p_f, p_o,
                                                tokQ, tokR, lenQ, lenR, hc, hn, cst, t);
  }

  // q_t = h_q @ M  (A = enc0 of buf0; B = M^T rows)
  k_gemm<1><<<dim3(8, 4), dim3(256), 0, stream>>>(hbuf, MT, qt, 1024, 1024);
  // distances = q_t @ h_r^T  (B rows = enc1 final h)
  k_gemm<0><<<dim3(4, 4), dim3(256), 0, stream>>>(qt, hbuf + (size_t)512 * 1024, out, 1024, 512);

  k_loss1<<<dim3(256), dim3(256), 0, stream>>>(out, part);
  k_loss2<<<dim3(1), dim3(256), 0, stream>>>(part, out + 262144);
}